// Round 7
// baseline (562.234 us; speedup 1.0000x reference)
//
#include <hip/hip_runtime.h>

typedef unsigned short ushort_t;
typedef __attribute__((ext_vector_type(8))) __bf16 bf16x8;
typedef __attribute__((ext_vector_type(8))) unsigned short ushort8;
typedef __attribute__((ext_vector_type(4))) unsigned short ushort4v;
typedef __attribute__((ext_vector_type(4))) float f32x4;

#define N_NODES 8192
#define NODE_MASK 8191
#define E_EDGES 32768
#define E_TOT   40960   /* E + N self loops */
#define M_MASK  2048
#define D_IN    768
#define C_CH    768
#define F1      6144    /* 8 heads * 768 */

typedef __attribute__((address_space(1))) const void* gas_ptr;
typedef __attribute__((address_space(3))) void* las_ptr;

__device__ __forceinline__ float bf2f(ushort_t u) {
    union { unsigned int i; float f; } v; v.i = ((unsigned int)u) << 16; return v.f;
}
__device__ __forceinline__ ushort_t f2bf(float f) {
    union { float f; unsigned int i; } v; v.f = f;
    unsigned int r = v.i + 0x7fffu + ((v.i >> 16) & 1u);
    return (ushort_t)(r >> 16);
}

// ---------------------------------------------------------------------------
// int64-vs-int32 detection + conversion of index arrays (clamped to [0,N)).
// ---------------------------------------------------------------------------
__global__ void init_kernel(int* deg, int* fill, int* flags) {
    int i = blockIdx.x * 256 + threadIdx.x;
    if (i < N_NODES) { deg[i] = 0; fill[i] = 0; }
    if (i < 2) flags[i] = 0;
}
__global__ void detect_kernel(const int* __restrict__ raw, int nhalf, int* __restrict__ flag) {
    int i = blockIdx.x * 256 + threadIdx.x;
    if (i < nhalf && raw[2 * i + 1] != 0) atomicOr(flag, 1);
}
__global__ void convert_idx_kernel(const void* __restrict__ raw, int n,
                                   const int* __restrict__ flag, int* __restrict__ out) {
    int i = blockIdx.x * 256 + threadIdx.x;
    if (i >= n) return;
    int v = (*flag) ? ((const int*)raw)[i] : (int)((const long long*)raw)[i];
    out[i] = v & NODE_MASK;
}

// ---------------------------------------------------------------------------
// f32 -> bf16 elementwise convert (vectorized)
// ---------------------------------------------------------------------------
__global__ void cvt_bf16_kernel(const float* __restrict__ in, ushort_t* __restrict__ out, int n4) {
    int i = blockIdx.x * 256 + threadIdx.x;
    if (i >= n4) return;
    f32x4 v = *(const f32x4*)(in + i * 4);
    ushort_t o0 = f2bf(v[0]), o1 = f2bf(v[1]), o2 = f2bf(v[2]), o3 = f2bf(v[3]);
    unsigned long long pk = (unsigned long long)o0 | ((unsigned long long)o1 << 16)
                          | ((unsigned long long)o2 << 32) | ((unsigned long long)o3 << 48);
    *(unsigned long long*)(out + i * 4) = pk;
}

// ---------------------------------------------------------------------------
// f32 -> bf16 transpose: out[c][r] = (bf16)in[r][c]; in is R x Ccols f32.
// ---------------------------------------------------------------------------
__global__ __launch_bounds__(256) void transpose_cvt_kernel(
    const float* __restrict__ in, ushort_t* __restrict__ out, int R, int Ccols)
{
    __shared__ ushort_t tile[32][33];
    int tx = threadIdx.x & 31, ty = threadIdx.x >> 5;
    int x  = blockIdx.x * 32 + tx;
    int y0 = blockIdx.y * 32;
#pragma unroll
    for (int i = 0; i < 4; ++i)
        tile[ty + i * 8][tx] = f2bf(in[(size_t)(y0 + ty + i * 8) * Ccols + x]);
    __syncthreads();
#pragma unroll
    for (int i = 0; i < 4; ++i)
        out[(size_t)(blockIdx.x * 32 + ty + i * 8) * R + y0 + tx] = tile[tx][ty + i * 8];
}

// ---------------------------------------------------------------------------
// bf16 MFMA GEMM:  C[M,N] = A[M,K]*Bt[N,K]^T (+ optional f32 bias[N]) -> bf16
// 128x128 tile, BK=64, 256 threads, global_load_lds w=16 staging, XOR swizzle
// on global source address. XCD-aware block remap (bijective; GY % 8 == 0 for
// the big grids, GY=16 uses byg=2): xcd = lin&7 owns a contiguous by-chunk so
// its A-row tiles stay resident in that XCD's 4MB L2.
// ---------------------------------------------------------------------------
__global__ __launch_bounds__(256) void gemm_bt_kernel(
    const ushort_t* __restrict__ A, const ushort_t* __restrict__ Bt,
    ushort_t* __restrict__ C, const float* __restrict__ bias,
    int M, int N, int K)
{
    __shared__ ushort_t lsA[128 * 64];
    __shared__ ushort_t lsB[128 * 64];

    const int tid  = threadIdx.x;
    const int lane = tid & 63;
    const int wave = tid >> 6;
    const int wm = wave >> 1, wn = wave & 1;

    // XCD-aware swizzle (dispatch linearizes x-fastest; XCD = lin%8)
    const int GX = gridDim.x, GY = gridDim.y;
    const int lin = blockIdx.y * GX + blockIdx.x;
    const int byg = (GY >= 8) ? (GY >> 3) : 1;
    const int xcd = lin & 7;
    const int jj  = lin >> 3;
    const int bx  = jj / byg;
    const int by  = (GY >= 8) ? (xcd * byg + (jj % byg)) : blockIdx.y;
    // (GY<8 never occurs in this launch set; guard keeps the remap total)

    const f32x4 zero = {0.f, 0.f, 0.f, 0.f};
    f32x4 acc[4][4];
#pragma unroll
    for (int i = 0; i < 4; ++i)
#pragma unroll
        for (int j = 0; j < 4; ++j) acc[i][j] = zero;

    const int l8 = lane >> 3;   // row within 8-row group
    const int c8 = lane & 7;    // 16B chunk slot
    const int q  = lane >> 4;   // quad
    const int rl = lane & 15;

    for (int kt = 0; kt < K; kt += 64) {
        __syncthreads();   // previous tile fully consumed
#pragma unroll
        for (int i = 0; i < 4; ++i) {
            int rbase = wave * 32 + i * 8;      // wave-uniform
            int row   = rbase + l8;             // per-lane
            int gch   = c8 ^ (row & 7);         // swizzle on source
            const ushort_t* gA = A  + (size_t)(by * 128 + row) * K + kt + gch * 8;
            const ushort_t* gB = Bt + (size_t)(bx * 128 + row) * K + kt + gch * 8;
            __builtin_amdgcn_global_load_lds((gas_ptr)gA, (las_ptr)(lsA + rbase * 64), 16, 0, 0);
            __builtin_amdgcn_global_load_lds((gas_ptr)gB, (las_ptr)(lsB + rbase * 64), 16, 0, 0);
        }
        __syncthreads();   // vmcnt drained by barrier semantics
#pragma unroll
        for (int s = 0; s < 2; ++s) {
            bf16x8 af[4], bfv[4];
#pragma unroll
            for (int i = 0; i < 4; ++i) {
                int Ra = wm * 64 + i * 16 + rl;
                af[i]  = *(const bf16x8*)(lsA + Ra * 64 + (((s * 4 + q) ^ (Ra & 7)) * 8));
                int Rb = wn * 64 + i * 16 + rl;
                bfv[i] = *(const bf16x8*)(lsB + Rb * 64 + (((s * 4 + q) ^ (Rb & 7)) * 8));
            }
#pragma unroll
            for (int i = 0; i < 4; ++i)
#pragma unroll
                for (int j = 0; j < 4; ++j)
                    acc[i][j] = __builtin_amdgcn_mfma_f32_16x16x32_bf16(af[i], bfv[j], acc[i][j], 0, 0, 0);
        }
    }
    // epilogue: C/D layout col=lane&15, row=quad*4+reg (m89-verified)
#pragma unroll
    for (int j = 0; j < 4; ++j) {
        int col = bx * 128 + wn * 64 + j * 16 + rl;
        float bv = bias ? bias[col] : 0.0f;
#pragma unroll
        for (int i = 0; i < 4; ++i) {
#pragma unroll
            for (int t = 0; t < 4; ++t) {
                int row = by * 128 + wm * 64 + i * 16 + q * 4 + t;
                C[(size_t)row * N + col] = f2bf(acc[i][j][t] + bv);
            }
        }
    }
}

// ---------------------------------------------------------------------------
// CSR build by dst (count -> scan -> scatter). Indices pre-clamped to [0,N).
// ---------------------------------------------------------------------------
__global__ void indeg_kernel(const int* __restrict__ eic, int* __restrict__ deg) {
    int e = blockIdx.x * 256 + threadIdx.x;
    if (e >= E_TOT) return;
    int dst = (e < E_EDGES) ? eic[E_EDGES + e] : (e - E_EDGES);
    atomicAdd(&deg[dst], 1);
}
__global__ __launch_bounds__(256) void scan_kernel(const int* __restrict__ deg, int* __restrict__ rowptr) {
    __shared__ int part[256];
    int t = threadIdx.x;
    int local[32];
    int s = 0;
#pragma unroll
    for (int i = 0; i < 32; ++i) { local[i] = deg[t * 32 + i]; s += local[i]; }
    part[t] = s;
    __syncthreads();
    for (int off = 1; off < 256; off <<= 1) {
        int v = (t >= off) ? part[t - off] : 0;
        __syncthreads();
        part[t] += v;
        __syncthreads();
    }
    int run = (t == 0) ? 0 : part[t - 1];
#pragma unroll
    for (int i = 0; i < 32; ++i) { rowptr[t * 32 + i] = run; run += local[i]; }
    if (t == 255) rowptr[N_NODES] = run;
}
__global__ void scatter_kernel(const int* __restrict__ eic, const int* __restrict__ rowptr,
                               int* __restrict__ fill, int* __restrict__ csr_src) {
    int e = blockIdx.x * 256 + threadIdx.x;
    if (e >= E_TOT) return;
    int src, dst;
    if (e < E_EDGES) { src = eic[e]; dst = eic[E_EDGES + e]; }
    else             { src = e - E_EDGES; dst = src; }
    int pos = rowptr[dst] + atomicAdd(&fill[dst], 1);
    csr_src[pos] = src;
}

// ---------------------------------------------------------------------------
// Attention logits: a_s[n,h] = <h[n,h,:], att_s[h,:]> (h bf16, att f32).
// One wave per (node, head); lane owns 3 x ushort4 (12 ch).
// ---------------------------------------------------------------------------
__global__ __launch_bounds__(256) void att_kernel(
    const ushort_t* __restrict__ h, const float* __restrict__ att_s,
    const float* __restrict__ att_d, float* __restrict__ a_s, float* __restrict__ a_d,
    int heads, int stride)
{
    int gid  = blockIdx.x * 4 + (threadIdx.x >> 6);
    int lane = threadIdx.x & 63;
    int n = gid / heads, hd = gid % heads;
    const ushort_t* hp = h + (size_t)n * stride + hd * C_CH;
    const float* sp = att_s + hd * C_CH;
    const float* dp = att_d + hd * C_CH;
    float s1 = 0.f, s2 = 0.f;
#pragma unroll
    for (int j = 0; j < 3; ++j) {
        int o = j * 256 + lane * 4;
        ushort4v hv = *(const ushort4v*)(hp + o);
        f32x4 sv = *(const f32x4*)(sp + o);
        f32x4 dv = *(const f32x4*)(dp + o);
#pragma unroll
        for (int k = 0; k < 4; ++k) {
            float f = bf2f(hv[k]);
            s1 += f * sv[k];
            s2 += f * dv[k];
        }
    }
#pragma unroll
    for (int off = 32; off > 0; off >>= 1) {
        s1 += __shfl_down(s1, off);
        s2 += __shfl_down(s2, off);
    }
    if (lane == 0) { a_s[gid] = s1; a_d[gid] = s2; }
}

// ---------------------------------------------------------------------------
// Aggregation layer 1 (8 heads, 6144 ch): grid (node, half). 192 thr x 16 ch;
// per-head softmax over incoming edges; edge loop unrolled x4; ELU -> bf16.
// ---------------------------------------------------------------------------
__global__ __launch_bounds__(192) void agg8_kernel(
    const ushort_t* __restrict__ h, const float* __restrict__ a_s, const float* __restrict__ a_d,
    const int* __restrict__ rowptr, const int* __restrict__ csr_src,
    const float* __restrict__ bias, ushort_t* __restrict__ out)
{
    const int n = blockIdx.x;
    const int half = blockIdx.y;
    const int tid = threadIdx.x;
    const int base = rowptr[n];
    const int deg  = rowptr[n + 1] - base;

    __shared__ float s_m[8], s_rd[8], s_adst[8];
    __shared__ int   s_src[64];
    __shared__ float s_w[64][8];

    if (tid < 8) {
        float adst = a_d[n * 8 + tid];
        float m = -1e30f;
        for (int e = 0; e < deg; ++e) {
            float scv = a_s[csr_src[base + e] * 8 + tid] + adst;
            scv = scv > 0.f ? scv : 0.2f * scv;
            m = fmaxf(m, scv);
        }
        float den = 0.f;
        for (int e = 0; e < deg; ++e) {
            float scv = a_s[csr_src[base + e] * 8 + tid] + adst;
            scv = scv > 0.f ? scv : 0.2f * scv;
            den += __expf(scv - m);
        }
        s_m[tid] = m; s_rd[tid] = 1.0f / (den + 1e-16f); s_adst[tid] = adst;
    }
    __syncthreads();

    float acc[16];
#pragma unroll
    for (int i = 0; i < 16; ++i) acc[i] = 0.f;
    const int c0   = half * 3072 + tid * 16;
    const int myhd = (half << 2) + tid / 48;

    for (int cs = 0; cs < deg; cs += 64) {
        int cnt = min(64, deg - cs);
        __syncthreads();
        for (int idx = tid; idx < cnt; idx += 192) s_src[idx] = csr_src[base + cs + idx];
        __syncthreads();
        for (int idx = tid; idx < cnt * 8; idx += 192) {
            int e = idx >> 3, hd = idx & 7;
            float scv = a_s[s_src[e] * 8 + hd] + s_adst[hd];
            scv = scv > 0.f ? scv : 0.2f * scv;
            s_w[e][hd] = __expf(scv - s_m[hd]) * s_rd[hd];
        }
        __syncthreads();
        int e = 0;
        for (; e + 3 < cnt; e += 4) {
            const ushort_t* p0 = h + (size_t)s_src[e]     * F1 + c0;
            const ushort_t* p1 = h + (size_t)s_src[e + 1] * F1 + c0;
            const ushort_t* p2 = h + (size_t)s_src[e + 2] * F1 + c0;
            const ushort_t* p3 = h + (size_t)s_src[e + 3] * F1 + c0;
            ushort8 a0 = *(const ushort8*)(p0), a1 = *(const ushort8*)(p0 + 8);
            ushort8 b0 = *(const ushort8*)(p1), b1 = *(const ushort8*)(p1 + 8);
            ushort8 c0v = *(const ushort8*)(p2), c1v = *(const ushort8*)(p2 + 8);
            ushort8 d0 = *(const ushort8*)(p3), d1 = *(const ushort8*)(p3 + 8);
            float w0 = s_w[e][myhd], w1 = s_w[e + 1][myhd];
            float w2 = s_w[e + 2][myhd], w3 = s_w[e + 3][myhd];
#pragma unroll
            for (int i = 0; i < 8; ++i) {
                acc[i]     += w0 * bf2f(a0[i]) + w1 * bf2f(b0[i]) + w2 * bf2f(c0v[i]) + w3 * bf2f(d0[i]);
                acc[8 + i] += w0 * bf2f(a1[i]) + w1 * bf2f(b1[i]) + w2 * bf2f(c1v[i]) + w3 * bf2f(d1[i]);
            }
        }
        for (; e < cnt; ++e) {
            const ushort_t* p0 = h + (size_t)s_src[e] * F1 + c0;
            ushort8 a0 = *(const ushort8*)(p0), a1 = *(const ushort8*)(p0 + 8);
            float w0 = s_w[e][myhd];
#pragma unroll
            for (int i = 0; i < 8; ++i) {
                acc[i]     += w0 * bf2f(a0[i]);
                acc[8 + i] += w0 * bf2f(a1[i]);
            }
        }
    }
#pragma unroll
    for (int i = 0; i < 16; ++i) {
        float v = acc[i] + bias[c0 + i];
        v = v > 0.f ? v : (__expf(v) - 1.0f);   // ELU
        out[(size_t)n * F1 + c0 + i] = f2bf(v);
    }
}

// ---------------------------------------------------------------------------
// Aggregation layer 2 (1 head, 768 ch): block per node, + b2, no activation.
// ---------------------------------------------------------------------------
__global__ __launch_bounds__(256) void agg1_kernel(
    const ushort_t* __restrict__ h, const float* __restrict__ a_s, const float* __restrict__ a_d,
    const int* __restrict__ rowptr, const int* __restrict__ csr_src,
    const float* __restrict__ bias, ushort_t* __restrict__ out)
{
    const int n = blockIdx.x;
    const int tid = threadIdx.x;
    const int base = rowptr[n];
    const int deg  = rowptr[n + 1] - base;
    __shared__ float s_m, s_rd, s_adst;
    __shared__ int   s_src[64];
    __shared__ float s_w[64];
    if (tid == 0) {
        float adst = a_d[n];
        float m = -1e30f;
        for (int e = 0; e < deg; ++e) {
            float scv = a_s[csr_src[base + e]] + adst;
            scv = scv > 0.f ? scv : 0.2f * scv;
            m = fmaxf(m, scv);
        }
        float den = 0.f;
        for (int e = 0; e < deg; ++e) {
            float scv = a_s[csr_src[base + e]] + adst;
            scv = scv > 0.f ? scv : 0.2f * scv;
            den += __expf(scv - m);
        }
        s_m = m; s_rd = 1.0f / (den + 1e-16f); s_adst = adst;
    }
    __syncthreads();
    float acc0 = 0.f, acc1 = 0.f, acc2 = 0.f;
    const int c0 = tid * 3;
    for (int cs = 0; cs < deg; cs += 64) {
        int cnt = min(64, deg - cs);
        __syncthreads();
        for (int idx = tid; idx < cnt; idx += 256) s_src[idx] = csr_src[base + cs + idx];
        __syncthreads();
        for (int idx = tid; idx < cnt; idx += 256) {
            float scv = a_s[s_src[idx]] + s_adst;
            scv = scv > 0.f ? scv : 0.2f * scv;
            s_w[idx] = __expf(scv - s_m) * s_rd;
        }
        __syncthreads();
        for (int e = 0; e < cnt; ++e) {
            const ushort_t* hp = h + (size_t)s_src[e] * C_CH + c0;
            float w = s_w[e];
            acc0 += w * bf2f(hp[0]);
            acc1 += w * bf2f(hp[1]);
            acc2 += w * bf2f(hp[2]);
        }
    }
    out[(size_t)n * C_CH + c0 + 0] = f2bf(acc0 + bias[c0 + 0]);
    out[(size_t)n * C_CH + c0 + 1] = f2bf(acc1 + bias[c0 + 1]);
    out[(size_t)n * C_CH + c0 + 2] = f2bf(acc2 + bias[c0 + 2]);
}

// ---------------------------------------------------------------------------
// Build fc input rows: Afc[m] = concat(out2[mask[m]], xb[mask[m]])  (bf16)
// ---------------------------------------------------------------------------
__global__ void gatherfc_kernel(const ushort_t* __restrict__ out2, const ushort_t* __restrict__ xb,
                                const int* __restrict__ maskc, ushort_t* __restrict__ Afc)
{
    int m = blockIdx.x, t = threadIdx.x;
    int mi = maskc[m];
    const ushort4v* p1 = (const ushort4v*)(out2 + (size_t)mi * 768);
    const ushort4v* p2 = (const ushort4v*)(xb   + (size_t)mi * 768);
    ushort4v* q1 = (ushort4v*)(Afc + (size_t)m * 1536);
    ushort4v* q2 = (ushort4v*)(Afc + (size_t)m * 1536 + 768);
    if (t < 192) { q1[t] = p1[t]; q2[t] = p2[t]; }
}

// ---------------------------------------------------------------------------
// Classifier: out[m, 0:2] = fc_out[m] @ cls_w + cls_b (f32 out). One wave/row.
// ---------------------------------------------------------------------------
__global__ __launch_bounds__(256) void cls_kernel(
    const ushort_t* __restrict__ fc_out, const float* __restrict__ cls_w,
    const float* __restrict__ cls_b, float* __restrict__ out)
{
    int m = blockIdx.x * 4 + (threadIdx.x >> 6);
    int lane = threadIdx.x & 63;
    float a0 = 0.f, a1 = 0.f;
    const ushort_t* row = fc_out + (size_t)m * 768;
    for (int i = lane; i < 768; i += 64) {
        float v = bf2f(row[i]);
        a0 += v * cls_w[i * 2 + 0];
        a1 += v * cls_w[i * 2 + 1];
    }
#pragma unroll
    for (int off = 32; off > 0; off >>= 1) {
        a0 += __shfl_down(a0, off);
        a1 += __shfl_down(a1, off);
    }
    if (lane == 0) {
        out[m * 2 + 0] = a0 + cls_b[0];
        out[m * 2 + 1] = a1 + cls_b[1];
    }
}

extern "C" void kernel_launch(void* const* d_in, const int* in_sizes, int n_in,
                              void* d_out, int out_size, void* d_ws, size_t ws_size,
                              hipStream_t stream)
{
    const float* x        = (const float*)d_in[0];
    const void*  ei_raw   = d_in[1];
    const void*  mask_raw = d_in[2];
    const float* W1       = (const float*)d_in[3];
    const float* att_src1 = (const float*)d_in[4];
    const float* att_dst1 = (const float*)d_in[5];
    const float* b1       = (const float*)d_in[6];
    const float* W2       = (const float*)d_in[7];
    const float* att_src2 = (const float*)d_in[8];
    const float* att_dst2 = (const float*)d_in[9];
    const float* b2       = (const float*)d_in[10];
    const float* fc_w     = (const float*)d_in[11];
    const float* fc_b     = (const float*)d_in[12];
    const float* cls_w    = (const float*)d_in[13];
    const float* cls_b    = (const float*)d_in[14];
    float* out = (float*)d_out;

    // ---- workspace layout (identical to round-4-proven map) ----
    char* ws = (char*)d_ws;
    size_t off = 0;
    auto alloc = [&](size_t bytes) { char* p = ws + off; off = (off + bytes + 255) & ~(size_t)255; return p; };
    int*   flags  = (int*)alloc(2 * 4);
    int*   eic    = (int*)alloc((size_t)2 * E_EDGES * 4);
    int*   maskc  = (int*)alloc((size_t)M_MASK * 4);
    int*   deg    = (int*)alloc(N_NODES * 4);
    int*   fill   = (int*)alloc(N_NODES * 4);
    int*   rowptr = (int*)alloc((N_NODES + 1) * 4);
    int*   csr    = (int*)alloc(E_TOT * 4);
    float* a_s1   = (float*)alloc((size_t)N_NODES * 8 * 4);
    float* a_d1   = (float*)alloc((size_t)N_NODES * 8 * 4);
    float* a_s2   = (float*)alloc((size_t)N_NODES * 4);
    float* a_d2   = (float*)alloc((size_t)N_NODES * 4);
    ushort_t* W1t  = (ushort_t*)alloc((size_t)D_IN * F1 * 2);
    ushort_t* W2t  = (ushort_t*)alloc((size_t)F1 * C_CH * 2);
    ushort_t* fcwt = (ushort_t*)alloc((size_t)1536 * 768 * 2);
    ushort_t* xb   = (ushort_t*)alloc((size_t)N_NODES * D_IN * 2);
    char* region1 = alloc((size_t)N_NODES * F1 * 2);   // h1, later h2/Afc/fcout
    char* region2 = alloc((size_t)N_NODES * F1 * 2);   // out1, later out2
    ushort_t* h1    = (ushort_t*)region1;
    ushort_t* h2    = (ushort_t*)region1;                   // after h1 dead (12.6MB)
    ushort_t* Afc   = (ushort_t*)(region1 + (16u << 20));   // 6.3MB @ 16MiB
    ushort_t* fcout = (ushort_t*)(region1 + (32u << 20));   // 3.1MB @ 32MiB
    ushort_t* out1  = (ushort_t*)region2;
    ushort_t* out2  = (ushort_t*)region2;                   // after out1 dead

    // ---- index conversion + CSR build ----
    init_kernel<<<N_NODES / 256, 256, 0, stream>>>(deg, fill, flags);
    detect_kernel<<<(E_EDGES + 255) / 256, 256, 0, stream>>>((const int*)ei_raw, E_EDGES, &flags[0]);
    detect_kernel<<<(M_MASK / 2 + 255) / 256, 256, 0, stream>>>((const int*)mask_raw, M_MASK / 2, &flags[1]);
    convert_idx_kernel<<<(2 * E_EDGES + 255) / 256, 256, 0, stream>>>(ei_raw, 2 * E_EDGES, &flags[0], eic);
    convert_idx_kernel<<<(M_MASK + 255) / 256, 256, 0, stream>>>(mask_raw, M_MASK, &flags[1], maskc);
    indeg_kernel<<<E_TOT / 256, 256, 0, stream>>>(eic, deg);
    scan_kernel<<<1, 256, 0, stream>>>(deg, rowptr);
    scatter_kernel<<<E_TOT / 256, 256, 0, stream>>>(eic, rowptr, fill, csr);

    // ---- f32 -> bf16 converts: x, and weight transposes to [N,K] ----
    cvt_bf16_kernel<<<(N_NODES * D_IN / 4 + 255) / 256, 256, 0, stream>>>(x, xb, N_NODES * D_IN / 4);
    transpose_cvt_kernel<<<dim3(F1 / 32, D_IN / 32), 256, 0, stream>>>(W1, W1t, D_IN, F1);
    transpose_cvt_kernel<<<dim3(C_CH / 32, F1 / 32), 256, 0, stream>>>(W2, W2t, F1, C_CH);
    transpose_cvt_kernel<<<dim3(768 / 32, 1536 / 32), 256, 0, stream>>>(fc_w, fcwt, 1536, 768);

    // ---- layer 1 ----
    gemm_bt_kernel<<<dim3(F1 / 128, N_NODES / 128), 256, 0, stream>>>(xb, W1t, h1, nullptr, N_NODES, F1, D_IN);
    att_kernel<<<(N_NODES * 8) / 4, 256, 0, stream>>>(h1, att_src1, att_dst1, a_s1, a_d1, 8, F1);
    agg8_kernel<<<dim3(N_NODES, 2), 192, 0, stream>>>(h1, a_s1, a_d1, rowptr, csr, b1, out1);

    // ---- layer 2 ----  (h1 dead: region1 reused for h2)
    gemm_bt_kernel<<<dim3(C_CH / 128, N_NODES / 128), 256, 0, stream>>>(out1, W2t, h2, nullptr, N_NODES, C_CH, F1);
    att_kernel<<<N_NODES / 4, 256, 0, stream>>>(h2, att_src2, att_dst2, a_s2, a_d2, 1, C_CH);
    agg1_kernel<<<N_NODES, 256, 0, stream>>>(h2, a_s2, a_d2, rowptr, csr, b2, out2);  // out1 dead

    // ---- head ----
    gatherfc_kernel<<<M_MASK, 256, 0, stream>>>(out2, xb, maskc, Afc);
    gemm_bt_kernel<<<dim3(768 / 128, M_MASK / 128), 256, 0, stream>>>(Afc, fcwt, fcout, fc_b, M_MASK, 768, 1536);
    cls_kernel<<<M_MASK / 4, 256, 0, stream>>>(fcout, cls_w, cls_b, out);
}

// Round 8
// 553.333 us; speedup vs baseline: 1.0161x; 1.0161x over previous
//
#include <hip/hip_runtime.h>

typedef unsigned short ushort_t;
typedef __attribute__((ext_vector_type(8))) __bf16 bf16x8;
typedef __attribute__((ext_vector_type(8))) unsigned short ushort8;
typedef __attribute__((ext_vector_type(4))) unsigned short ushort4v;
typedef __attribute__((ext_vector_type(4))) float f32x4;

#define N_NODES 8192
#define NODE_MASK 8191
#define E_EDGES 32768
#define E_TOT   40960   /* E + N self loops */
#define M_MASK  2048
#define D_IN    768
#define C_CH    768
#define F1      6144    /* 8 heads * 768 */

typedef __attribute__((address_space(1))) const void* gas_ptr;
typedef __attribute__((address_space(3))) void* las_ptr;

__device__ __forceinline__ float bf2f(ushort_t u) {
    union { unsigned int i; float f; } v; v.i = ((unsigned int)u) << 16; return v.f;
}
__device__ __forceinline__ ushort_t f2bf(float f) {
    union { float f; unsigned int i; } v; v.f = f;
    unsigned int r = v.i + 0x7fffu + ((v.i >> 16) & 1u);
    return (ushort_t)(r >> 16);
}

// ---------------------------------------------------------------------------
// int64-vs-int32 detection + conversion of index arrays (clamped to [0,N)).
// ---------------------------------------------------------------------------
__global__ void init_kernel(int* deg, int* fill, int* flags) {
    int i = blockIdx.x * 256 + threadIdx.x;
    if (i < N_NODES) { deg[i] = 0; fill[i] = 0; }
    if (i < 2) flags[i] = 0;
}
__global__ void detect_kernel(const int* __restrict__ raw, int nhalf, int* __restrict__ flag) {
    int i = blockIdx.x * 256 + threadIdx.x;
    if (i < nhalf && raw[2 * i + 1] != 0) atomicOr(flag, 1);
}
__global__ void convert_idx_kernel(const void* __restrict__ raw, int n,
                                   const int* __restrict__ flag, int* __restrict__ out) {
    int i = blockIdx.x * 256 + threadIdx.x;
    if (i >= n) return;
    int v = (*flag) ? ((const int*)raw)[i] : (int)((const long long*)raw)[i];
    out[i] = v & NODE_MASK;
}

// ---------------------------------------------------------------------------
// f32 -> bf16 elementwise convert (vectorized)
// ---------------------------------------------------------------------------
__global__ void cvt_bf16_kernel(const float* __restrict__ in, ushort_t* __restrict__ out, int n4) {
    int i = blockIdx.x * 256 + threadIdx.x;
    if (i >= n4) return;
    f32x4 v = *(const f32x4*)(in + i * 4);
    ushort_t o0 = f2bf(v[0]), o1 = f2bf(v[1]), o2 = f2bf(v[2]), o3 = f2bf(v[3]);
    unsigned long long pk = (unsigned long long)o0 | ((unsigned long long)o1 << 16)
                          | ((unsigned long long)o2 << 32) | ((unsigned long long)o3 << 48);
    *(unsigned long long*)(out + i * 4) = pk;
}

// ---------------------------------------------------------------------------
// f32 -> bf16 transpose: out[c][r] = (bf16)in[r][c]; in is R x Ccols f32.
// ---------------------------------------------------------------------------
__global__ __launch_bounds__(256) void transpose_cvt_kernel(
    const float* __restrict__ in, ushort_t* __restrict__ out, int R, int Ccols)
{
    __shared__ ushort_t tile[32][33];
    int tx = threadIdx.x & 31, ty = threadIdx.x >> 5;
    int x  = blockIdx.x * 32 + tx;
    int y0 = blockIdx.y * 32;
#pragma unroll
    for (int i = 0; i < 4; ++i)
        tile[ty + i * 8][tx] = f2bf(in[(size_t)(y0 + ty + i * 8) * Ccols + x]);
    __syncthreads();
#pragma unroll
    for (int i = 0; i < 4; ++i)
        out[(size_t)(blockIdx.x * 32 + ty + i * 8) * R + y0 + tx] = tile[tx][ty + i * 8];
}

// ---------------------------------------------------------------------------
// bf16 MFMA GEMM:  C[M,N] = A[M,K]*Bt[N,K]^T.  128x128 tile, BK=64, 256 thr,
// global_load_lds w=16 staging, XOR swizzle on global source address.
// XCD-aware block remap (bijective): xcd = lin&7 owns a contiguous by-chunk.
// Split-K: z-slice covers [k0 + z*ksz, k0 + (z+1)*ksz); non-split: z=0, ksz=K.
// Epilogue: bf16 C (+f32 bias)  OR  f32 slice Cp + z*M*N (plain stores).
// ---------------------------------------------------------------------------
__global__ __launch_bounds__(256) void gemm_bt_kernel(
    const ushort_t* __restrict__ A, const ushort_t* __restrict__ Bt,
    ushort_t* __restrict__ C, const float* __restrict__ bias,
    float* __restrict__ Cp,
    int M, int N, int K, int k0, int ksz)
{
    __shared__ ushort_t lsA[128 * 64];
    __shared__ ushort_t lsB[128 * 64];

    const int tid  = threadIdx.x;
    const int lane = tid & 63;
    const int wave = tid >> 6;
    const int wm = wave >> 1, wn = wave & 1;

    // XCD-aware swizzle (dispatch linearizes x-fastest; XCD = lin%8)
    const int GX = gridDim.x, GY = gridDim.y;
    const int lin = blockIdx.y * GX + blockIdx.x;
    const int byg = (GY >= 8) ? (GY >> 3) : 1;
    const int xcd = lin & 7;
    const int jj  = lin >> 3;
    const int bx  = (GY >= 8) ? (jj / byg) : blockIdx.x;
    const int by  = (GY >= 8) ? (xcd * byg + (jj % byg)) : blockIdx.y;

    const f32x4 zero = {0.f, 0.f, 0.f, 0.f};
    f32x4 acc[4][4];
#pragma unroll
    for (int i = 0; i < 4; ++i)
#pragma unroll
        for (int j = 0; j < 4; ++j) acc[i][j] = zero;

    const int l8 = lane >> 3;   // row within 8-row group
    const int c8 = lane & 7;    // 16B chunk slot
    const int q  = lane >> 4;   // quad
    const int rl = lane & 15;

    const int kbeg = k0 + blockIdx.z * ksz;
    for (int kt = kbeg; kt < kbeg + ksz; kt += 64) {
        __syncthreads();   // previous tile fully consumed
#pragma unroll
        for (int i = 0; i < 4; ++i) {
            int rbase = wave * 32 + i * 8;      // wave-uniform
            int row   = rbase + l8;             // per-lane
            int gch   = c8 ^ (row & 7);         // swizzle on source
            const ushort_t* gA = A  + (size_t)(by * 128 + row) * K + kt + gch * 8;
            const ushort_t* gB = Bt + (size_t)(bx * 128 + row) * K + kt + gch * 8;
            __builtin_amdgcn_global_load_lds((gas_ptr)gA, (las_ptr)(lsA + rbase * 64), 16, 0, 0);
            __builtin_amdgcn_global_load_lds((gas_ptr)gB, (las_ptr)(lsB + rbase * 64), 16, 0, 0);
        }
        __syncthreads();   // vmcnt drained by barrier semantics
#pragma unroll
        for (int s = 0; s < 2; ++s) {
            bf16x8 af[4], bfv[4];
#pragma unroll
            for (int i = 0; i < 4; ++i) {
                int Ra = wm * 64 + i * 16 + rl;
                af[i]  = *(const bf16x8*)(lsA + Ra * 64 + (((s * 4 + q) ^ (Ra & 7)) * 8));
                int Rb = wn * 64 + i * 16 + rl;
                bfv[i] = *(const bf16x8*)(lsB + Rb * 64 + (((s * 4 + q) ^ (Rb & 7)) * 8));
            }
#pragma unroll
            for (int i = 0; i < 4; ++i)
#pragma unroll
                for (int j = 0; j < 4; ++j)
                    acc[i][j] = __builtin_amdgcn_mfma_f32_16x16x32_bf16(af[i], bfv[j], acc[i][j], 0, 0, 0);
        }
    }
    // epilogue: C/D layout col=lane&15, row=quad*4+reg (m89-verified)
    if (Cp) {
        float* Cpz = Cp + (size_t)blockIdx.z * M * N;
#pragma unroll
        for (int j = 0; j < 4; ++j) {
            int col = bx * 128 + wn * 64 + j * 16 + rl;
#pragma unroll
            for (int i = 0; i < 4; ++i)
#pragma unroll
                for (int t = 0; t < 4; ++t) {
                    int row = by * 128 + wm * 64 + i * 16 + q * 4 + t;
                    Cpz[(size_t)row * N + col] = acc[i][j][t];
                }
        }
    } else {
#pragma unroll
        for (int j = 0; j < 4; ++j) {
            int col = bx * 128 + wn * 64 + j * 16 + rl;
            float bv = bias ? bias[col] : 0.0f;
#pragma unroll
            for (int i = 0; i < 4; ++i)
#pragma unroll
                for (int t = 0; t < 4; ++t) {
                    int row = by * 128 + wm * 64 + i * 16 + q * 4 + t;
                    C[(size_t)row * N + col] = f2bf(acc[i][j][t] + bv);
                }
        }
    }
}

// ---------------------------------------------------------------------------
// CSR build by dst (count -> scan -> scatter). Indices pre-clamped to [0,N).
// ---------------------------------------------------------------------------
__global__ void indeg_kernel(const int* __restrict__ eic, int* __restrict__ deg) {
    int e = blockIdx.x * 256 + threadIdx.x;
    if (e >= E_TOT) return;
    int dst = (e < E_EDGES) ? eic[E_EDGES + e] : (e - E_EDGES);
    atomicAdd(&deg[dst], 1);
}
__global__ __launch_bounds__(256) void scan_kernel(const int* __restrict__ deg, int* __restrict__ rowptr) {
    __shared__ int part[256];
    int t = threadIdx.x;
    int local[32];
    int s = 0;
#pragma unroll
    for (int i = 0; i < 32; ++i) { local[i] = deg[t * 32 + i]; s += local[i]; }
    part[t] = s;
    __syncthreads();
    for (int off = 1; off < 256; off <<= 1) {
        int v = (t >= off) ? part[t - off] : 0;
        __syncthreads();
        part[t] += v;
        __syncthreads();
    }
    int run = (t == 0) ? 0 : part[t - 1];
#pragma unroll
    for (int i = 0; i < 32; ++i) { rowptr[t * 32 + i] = run; run += local[i]; }
    if (t == 255) rowptr[N_NODES] = run;
}
__global__ void scatter_kernel(const int* __restrict__ eic, const int* __restrict__ rowptr,
                               int* __restrict__ fill, int* __restrict__ csr_src) {
    int e = blockIdx.x * 256 + threadIdx.x;
    if (e >= E_TOT) return;
    int src, dst;
    if (e < E_EDGES) { src = eic[e]; dst = eic[E_EDGES + e]; }
    else             { src = e - E_EDGES; dst = src; }
    int pos = rowptr[dst] + atomicAdd(&fill[dst], 1);
    csr_src[pos] = src;
}

// ---------------------------------------------------------------------------
// Attention logits (layer 1): a_s[n,h] = <h[n,h,:], att_s[h,:]>.
// One wave per (node, head); lane owns 3 x ushort4 (12 ch).
// ---------------------------------------------------------------------------
__global__ __launch_bounds__(256) void att_kernel(
    const ushort_t* __restrict__ h, const float* __restrict__ att_s,
    const float* __restrict__ att_d, float* __restrict__ a_s, float* __restrict__ a_d,
    int heads, int stride)
{
    int gid  = blockIdx.x * 4 + (threadIdx.x >> 6);
    int lane = threadIdx.x & 63;
    int n = gid / heads, hd = gid % heads;
    const ushort_t* hp = h + (size_t)n * stride + hd * C_CH;
    const float* sp = att_s + hd * C_CH;
    const float* dp = att_d + hd * C_CH;
    float s1 = 0.f, s2 = 0.f;
#pragma unroll
    for (int j = 0; j < 3; ++j) {
        int o = j * 256 + lane * 4;
        ushort4v hv = *(const ushort4v*)(hp + o);
        f32x4 sv = *(const f32x4*)(sp + o);
        f32x4 dv = *(const f32x4*)(dp + o);
#pragma unroll
        for (int k = 0; k < 4; ++k) {
            float f = bf2f(hv[k]);
            s1 += f * sv[k];
            s2 += f * dv[k];
        }
    }
#pragma unroll
    for (int off = 32; off > 0; off >>= 1) {
        s1 += __shfl_down(s1, off);
        s2 += __shfl_down(s2, off);
    }
    if (lane == 0) { a_s[gid] = s1; a_d[gid] = s2; }
}

// ---------------------------------------------------------------------------
// Split-K consumer: h2 = bf16(sum of 4 Cp slices) + fused layer-2 attention
// logits (1 head): a_s2[n] = <h2row, att_s2>. Block per node, 256 threads.
// ---------------------------------------------------------------------------
__global__ __launch_bounds__(256) void cvtatt_kernel(
    const float* __restrict__ Cp, ushort_t* __restrict__ h2,
    const float* __restrict__ att_s, const float* __restrict__ att_d,
    float* __restrict__ a_s, float* __restrict__ a_d)
{
    __shared__ float ps[4], pd[4];
    const int n = blockIdx.x, t = threadIdx.x;
    const size_t SL = (size_t)N_NODES * 768;
    const float* row = Cp + (size_t)n * 768;
    float v0 = row[t]       + row[SL + t]       + row[2 * SL + t]       + row[3 * SL + t];
    float v1 = row[t + 256] + row[SL + t + 256] + row[2 * SL + t + 256] + row[3 * SL + t + 256];
    float v2 = row[t + 512] + row[SL + t + 512] + row[2 * SL + t + 512] + row[3 * SL + t + 512];
    h2[(size_t)n * 768 + t]       = f2bf(v0);
    h2[(size_t)n * 768 + t + 256] = f2bf(v1);
    h2[(size_t)n * 768 + t + 512] = f2bf(v2);
    float s1 = v0 * att_s[t] + v1 * att_s[t + 256] + v2 * att_s[t + 512];
    float s2 = v0 * att_d[t] + v1 * att_d[t + 256] + v2 * att_d[t + 512];
#pragma unroll
    for (int o = 32; o > 0; o >>= 1) {
        s1 += __shfl_down(s1, o);
        s2 += __shfl_down(s2, o);
    }
    if ((t & 63) == 0) { ps[t >> 6] = s1; pd[t >> 6] = s2; }
    __syncthreads();
    if (t == 0) {
        a_s[n] = ps[0] + ps[1] + ps[2] + ps[3];
        a_d[n] = pd[0] + pd[1] + pd[2] + pd[3];
    }
}

// ---------------------------------------------------------------------------
// Aggregation layer 1 (8 heads, 6144 ch): grid (node, half). 192 thr x 16 ch;
// per-head softmax over incoming edges; edge loop unrolled x4; ELU -> bf16.
// ---------------------------------------------------------------------------
__global__ __launch_bounds__(192) void agg8_kernel(
    const ushort_t* __restrict__ h, const float* __restrict__ a_s, const float* __restrict__ a_d,
    const int* __restrict__ rowptr, const int* __restrict__ csr_src,
    const float* __restrict__ bias, ushort_t* __restrict__ out)
{
    const int n = blockIdx.x;
    const int half = blockIdx.y;
    const int tid = threadIdx.x;
    const int base = rowptr[n];
    const int deg  = rowptr[n + 1] - base;

    __shared__ float s_m[8], s_rd[8], s_adst[8];
    __shared__ int   s_src[64];
    __shared__ float s_w[64][8];

    if (tid < 8) {
        float adst = a_d[n * 8 + tid];
        float m = -1e30f;
        for (int e = 0; e < deg; ++e) {
            float scv = a_s[csr_src[base + e] * 8 + tid] + adst;
            scv = scv > 0.f ? scv : 0.2f * scv;
            m = fmaxf(m, scv);
        }
        float den = 0.f;
        for (int e = 0; e < deg; ++e) {
            float scv = a_s[csr_src[base + e] * 8 + tid] + adst;
            scv = scv > 0.f ? scv : 0.2f * scv;
            den += __expf(scv - m);
        }
        s_m[tid] = m; s_rd[tid] = 1.0f / (den + 1e-16f); s_adst[tid] = adst;
    }
    __syncthreads();

    float acc[16];
#pragma unroll
    for (int i = 0; i < 16; ++i) acc[i] = 0.f;
    const int c0   = half * 3072 + tid * 16;
    const int myhd = (half << 2) + tid / 48;

    for (int cs = 0; cs < deg; cs += 64) {
        int cnt = min(64, deg - cs);
        __syncthreads();
        for (int idx = tid; idx < cnt; idx += 192) s_src[idx] = csr_src[base + cs + idx];
        __syncthreads();
        for (int idx = tid; idx < cnt * 8; idx += 192) {
            int e = idx >> 3, hd = idx & 7;
            float scv = a_s[s_src[e] * 8 + hd] + s_adst[hd];
            scv = scv > 0.f ? scv : 0.2f * scv;
            s_w[e][hd] = __expf(scv - s_m[hd]) * s_rd[hd];
        }
        __syncthreads();
        int e = 0;
        for (; e + 3 < cnt; e += 4) {
            const ushort_t* p0 = h + (size_t)s_src[e]     * F1 + c0;
            const ushort_t* p1 = h + (size_t)s_src[e + 1] * F1 + c0;
            const ushort_t* p2 = h + (size_t)s_src[e + 2] * F1 + c0;
            const ushort_t* p3 = h + (size_t)s_src[e + 3] * F1 + c0;
            ushort8 a0 = *(const ushort8*)(p0), a1 = *(const ushort8*)(p0 + 8);
            ushort8 b0 = *(const ushort8*)(p1), b1 = *(const ushort8*)(p1 + 8);
            ushort8 c0v = *(const ushort8*)(p2), c1v = *(const ushort8*)(p2 + 8);
            ushort8 d0 = *(const ushort8*)(p3), d1 = *(const ushort8*)(p3 + 8);
            float w0 = s_w[e][myhd], w1 = s_w[e + 1][myhd];
            float w2 = s_w[e + 2][myhd], w3 = s_w[e + 3][myhd];
#pragma unroll
            for (int i = 0; i < 8; ++i) {
                acc[i]     += w0 * bf2f(a0[i]) + w1 * bf2f(b0[i]) + w2 * bf2f(c0v[i]) + w3 * bf2f(d0[i]);
                acc[8 + i] += w0 * bf2f(a1[i]) + w1 * bf2f(b1[i]) + w2 * bf2f(c1v[i]) + w3 * bf2f(d1[i]);
            }
        }
        for (; e < cnt; ++e) {
            const ushort_t* p0 = h + (size_t)s_src[e] * F1 + c0;
            ushort8 a0 = *(const ushort8*)(p0), a1 = *(const ushort8*)(p0 + 8);
            float w0 = s_w[e][myhd];
#pragma unroll
            for (int i = 0; i < 8; ++i) {
                acc[i]     += w0 * bf2f(a0[i]);
                acc[8 + i] += w0 * bf2f(a1[i]);
            }
        }
    }
#pragma unroll
    for (int i = 0; i < 16; ++i) {
        float v = acc[i] + bias[c0 + i];
        v = v > 0.f ? v : (__expf(v) - 1.0f);   // ELU
        out[(size_t)n * F1 + c0 + i] = f2bf(v);
    }
}

// ---------------------------------------------------------------------------
// Aggregation layer 2 (1 head, 768 ch): block per node, + b2, no activation.
// ---------------------------------------------------------------------------
__global__ __launch_bounds__(256) void agg1_kernel(
    const ushort_t* __restrict__ h, const float* __restrict__ a_s, const float* __restrict__ a_d,
    const int* __restrict__ rowptr, const int* __restrict__ csr_src,
    const float* __restrict__ bias, ushort_t* __restrict__ out)
{
    const int n = blockIdx.x;
    const int tid = threadIdx.x;
    const int base = rowptr[n];
    const int deg  = rowptr[n + 1] - base;
    __shared__ float s_m, s_rd, s_adst;
    __shared__ int   s_src[64];
    __shared__ float s_w[64];
    if (tid == 0) {
        float adst = a_d[n];
        float m = -1e30f;
        for (int e = 0; e < deg; ++e) {
            float scv = a_s[csr_src[base + e]] + adst;
            scv = scv > 0.f ? scv : 0.2f * scv;
            m = fmaxf(m, scv);
        }
        float den = 0.f;
        for (int e = 0; e < deg; ++e) {
            float scv = a_s[csr_src[base + e]] + adst;
            scv = scv > 0.f ? scv : 0.2f * scv;
            den += __expf(scv - m);
        }
        s_m = m; s_rd = 1.0f / (den + 1e-16f); s_adst = adst;
    }
    __syncthreads();
    float acc0 = 0.f, acc1 = 0.f, acc2 = 0.f;
    const int c0 = tid * 3;
    for (int cs = 0; cs < deg; cs += 64) {
        int cnt = min(64, deg - cs);
        __syncthreads();
        for (int idx = tid; idx < cnt; idx += 256) s_src[idx] = csr_src[base + cs + idx];
        __syncthreads();
        for (int idx = tid; idx < cnt; idx += 256) {
            float scv = a_s[s_src[idx]] + s_adst;
            scv = scv > 0.f ? scv : 0.2f * scv;
            s_w[idx] = __expf(scv - s_m) * s_rd;
        }
        __syncthreads();
        for (int e = 0; e < cnt; ++e) {
            const ushort_t* hp = h + (size_t)s_src[e] * C_CH + c0;
            float w = s_w[e];
            acc0 += w * bf2f(hp[0]);
            acc1 += w * bf2f(hp[1]);
            acc2 += w * bf2f(hp[2]);
        }
    }
    out[(size_t)n * C_CH + c0 + 0] = f2bf(acc0 + bias[c0 + 0]);
    out[(size_t)n * C_CH + c0 + 1] = f2bf(acc1 + bias[c0 + 1]);
    out[(size_t)n * C_CH + c0 + 2] = f2bf(acc2 + bias[c0 + 2]);
}

// ---------------------------------------------------------------------------
// Build fc input rows: Afc[m] = concat(out2[mask[m]], xb[mask[m]])  (bf16)
// ---------------------------------------------------------------------------
__global__ void gatherfc_kernel(const ushort_t* __restrict__ out2, const ushort_t* __restrict__ xb,
                                const int* __restrict__ maskc, ushort_t* __restrict__ Afc)
{
    int m = blockIdx.x, t = threadIdx.x;
    int mi = maskc[m];
    const ushort4v* p1 = (const ushort4v*)(out2 + (size_t)mi * 768);
    const ushort4v* p2 = (const ushort4v*)(xb   + (size_t)mi * 768);
    ushort4v* q1 = (ushort4v*)(Afc + (size_t)m * 1536);
    ushort4v* q2 = (ushort4v*)(Afc + (size_t)m * 1536 + 768);
    if (t < 192) { q1[t] = p1[t]; q2[t] = p2[t]; }
}

// ---------------------------------------------------------------------------
// Classifier over fc split-K slices: fcrow[c] = sum_z fcp[z][m*768+c] + fc_b[c];
// out[m,k] = <fcrow, cls_w[:,k]> + cls_b[k]. One wave per row.
// ---------------------------------------------------------------------------
__global__ __launch_bounds__(256) void cls_kernel(
    const float* __restrict__ fcp, const float* __restrict__ fc_b,
    const float* __restrict__ cls_w, const float* __restrict__ cls_b,
    float* __restrict__ out)
{
    int m = blockIdx.x * 4 + (threadIdx.x >> 6);
    int lane = threadIdx.x & 63;
    const size_t SL = (size_t)M_MASK * 768;
    float a0 = 0.f, a1 = 0.f;
    const float* row = fcp + (size_t)m * 768;
    for (int i = lane; i < 768; i += 64) {
        float v = row[i] + row[SL + i] + row[2 * SL + i] + row[3 * SL + i] + fc_b[i];
        a0 += v * cls_w[i * 2 + 0];
        a1 += v * cls_w[i * 2 + 1];
    }
#pragma unroll
    for (int off = 32; off > 0; off >>= 1) {
        a0 += __shfl_down(a0, off);
        a1 += __shfl_down(a1, off);
    }
    if (lane == 0) {
        out[m * 2 + 0] = a0 + cls_b[0];
        out[m * 2 + 1] = a1 + cls_b[1];
    }
}

extern "C" void kernel_launch(void* const* d_in, const int* in_sizes, int n_in,
                              void* d_out, int out_size, void* d_ws, size_t ws_size,
                              hipStream_t stream)
{
    const float* x        = (const float*)d_in[0];
    const void*  ei_raw   = d_in[1];
    const void*  mask_raw = d_in[2];
    const float* W1       = (const float*)d_in[3];
    const float* att_src1 = (const float*)d_in[4];
    const float* att_dst1 = (const float*)d_in[5];
    const float* b1       = (const float*)d_in[6];
    const float* W2       = (const float*)d_in[7];
    const float* att_src2 = (const float*)d_in[8];
    const float* att_dst2 = (const float*)d_in[9];
    const float* b2       = (const float*)d_in[10];
    const float* fc_w     = (const float*)d_in[11];
    const float* fc_b     = (const float*)d_in[12];
    const float* cls_w    = (const float*)d_in[13];
    const float* cls_b    = (const float*)d_in[14];
    float* out = (float*)d_out;

    // ---- workspace layout ----
    char* ws = (char*)d_ws;
    size_t off = 0;
    auto alloc = [&](size_t bytes) { char* p = ws + off; off = (off + bytes + 255) & ~(size_t)255; return p; };
    int*   flags  = (int*)alloc(2 * 4);
    int*   eic    = (int*)alloc((size_t)2 * E_EDGES * 4);
    int*   maskc  = (int*)alloc((size_t)M_MASK * 4);
    int*   deg    = (int*)alloc(N_NODES * 4);
    int*   fill   = (int*)alloc(N_NODES * 4);
    int*   rowptr = (int*)alloc((N_NODES + 1) * 4);
    int*   csr    = (int*)alloc(E_TOT * 4);
    float* a_s1   = (float*)alloc((size_t)N_NODES * 8 * 4);
    float* a_d1   = (float*)alloc((size_t)N_NODES * 8 * 4);
    float* a_s2   = (float*)alloc((size_t)N_NODES * 4);
    float* a_d2   = (float*)alloc((size_t)N_NODES * 4);
    ushort_t* W1t  = (ushort_t*)alloc((size_t)D_IN * F1 * 2);
    ushort_t* W2t  = (ushort_t*)alloc((size_t)F1 * C_CH * 2);
    ushort_t* fcwt = (ushort_t*)alloc((size_t)1536 * 768 * 2);
    ushort_t* xb   = (ushort_t*)alloc((size_t)N_NODES * D_IN * 2);
    char* region1 = alloc((size_t)N_NODES * F1 * 2);   // h1 -> Cp(4 slices) -> fcp
    char* region2 = alloc((size_t)N_NODES * F1 * 2);   // out1 -> {out2, h2, Afc}
    // region1 phases:
    ushort_t* h1  = (ushort_t*)region1;                 // layer-1 GEMM out (100.7MB)
    float*    Cp  = (float*)region1;                    // 4 x 25.2MB f32 split-K slices
    float*    fcp = (float*)region1;                    // 4 x 6.3MB fc split-K slices
    // region2 phases:
    ushort_t* out1 = (ushort_t*)region2;                // agg8 out (100.7MB), GEMM2 A
    ushort_t* out2 = (ushort_t*)region2;                // agg1 out (12.6MB), after out1 dead
    ushort_t* h2   = (ushort_t*)(region2 + (16u << 20)); // 12.6MB @ 16MiB
    ushort_t* Afc  = (ushort_t*)(region2 + (32u << 20)); // 6.3MB  @ 32MiB

    // ---- index conversion + CSR build ----
    init_kernel<<<N_NODES / 256, 256, 0, stream>>>(deg, fill, flags);
    detect_kernel<<<(E_EDGES + 255) / 256, 256, 0, stream>>>((const int*)ei_raw, E_EDGES, &flags[0]);
    detect_kernel<<<(M_MASK / 2 + 255) / 256, 256, 0, stream>>>((const int*)mask_raw, M_MASK / 2, &flags[1]);
    convert_idx_kernel<<<(2 * E_EDGES + 255) / 256, 256, 0, stream>>>(ei_raw, 2 * E_EDGES, &flags[0], eic);
    convert_idx_kernel<<<(M_MASK + 255) / 256, 256, 0, stream>>>(mask_raw, M_MASK, &flags[1], maskc);
    indeg_kernel<<<E_TOT / 256, 256, 0, stream>>>(eic, deg);
    scan_kernel<<<1, 256, 0, stream>>>(deg, rowptr);
    scatter_kernel<<<E_TOT / 256, 256, 0, stream>>>(eic, rowptr, fill, csr);

    // ---- f32 -> bf16 converts: x, and weight transposes to [N,K] ----
    cvt_bf16_kernel<<<(N_NODES * D_IN / 4 + 255) / 256, 256, 0, stream>>>(x, xb, N_NODES * D_IN / 4);
    transpose_cvt_kernel<<<dim3(F1 / 32, D_IN / 32), 256, 0, stream>>>(W1, W1t, D_IN, F1);
    transpose_cvt_kernel<<<dim3(C_CH / 32, F1 / 32), 256, 0, stream>>>(W2, W2t, F1, C_CH);
    transpose_cvt_kernel<<<dim3(768 / 32, 1536 / 32), 256, 0, stream>>>(fc_w, fcwt, 1536, 768);

    // ---- layer 1 ----
    gemm_bt_kernel<<<dim3(F1 / 128, N_NODES / 128), 256, 0, stream>>>(
        xb, W1t, h1, nullptr, nullptr, N_NODES, F1, D_IN, 0, D_IN);
    att_kernel<<<(N_NODES * 8) / 4, 256, 0, stream>>>(h1, att_src1, att_dst1, a_s1, a_d1, 8, F1);
    agg8_kernel<<<dim3(N_NODES, 2), 192, 0, stream>>>(h1, a_s1, a_d1, rowptr, csr, b1, out1);

    // ---- layer 2: split-K=4 into f32 slices (h1 dead), cvt+att2, aggregate ----
    gemm_bt_kernel<<<dim3(C_CH / 128, N_NODES / 128, 4), 256, 0, stream>>>(
        out1, W2t, nullptr, nullptr, Cp, N_NODES, C_CH, F1, 0, F1 / 4);
    cvtatt_kernel<<<N_NODES, 256, 0, stream>>>(Cp, h2, att_src2, att_dst2, a_s2, a_d2);
    agg1_kernel<<<N_NODES, 256, 0, stream>>>(h2, a_s2, a_d2, rowptr, csr, b2, out2);  // out1 dead

    // ---- head: gather, fc split-K=4 (Cp dead -> fcp), fused classifier ----
    gatherfc_kernel<<<M_MASK, 256, 0, stream>>>(out2, xb, maskc, Afc);
    gemm_bt_kernel<<<dim3(768 / 128, M_MASK / 128, 4), 256, 0, stream>>>(
        Afc, fcwt, nullptr, nullptr, fcp, M_MASK, 768, 1536, 0, 1536 / 4);
    cls_kernel<<<M_MASK / 4, 256, 0, stream>>>(fcp, fc_b, cls_w, cls_b, out);
}

// Round 9
// 551.624 us; speedup vs baseline: 1.0192x; 1.0031x over previous
//
#include <hip/hip_runtime.h>

typedef unsigned short ushort_t;
typedef __attribute__((ext_vector_type(8))) __bf16 bf16x8;
typedef __attribute__((ext_vector_type(8))) unsigned short ushort8;
typedef __attribute__((ext_vector_type(4))) unsigned short ushort4v;
typedef __attribute__((ext_vector_type(4))) float f32x4;

#define N_NODES 8192
#define NODE_MASK 8191
#define E_EDGES 32768
#define E_TOT   40960   /* E + N self loops */
#define M_MASK  2048
#define D_IN    768
#define C_CH    768
#define F1      6144    /* 8 heads * 768 */

typedef __attribute__((address_space(1))) const void* gas_ptr;
typedef __attribute__((address_space(3))) void* las_ptr;

__device__ __forceinline__ float bf2f(ushort_t u) {
    union { unsigned int i; float f; } v; v.i = ((unsigned int)u) << 16; return v.f;
}
__device__ __forceinline__ ushort_t f2bf(float f) {
    union { float f; unsigned int i; } v; v.f = f;
    unsigned int r = v.i + 0x7fffu + ((v.i >> 16) & 1u);
    return (ushort_t)(r >> 16);
}

// ---------------------------------------------------------------------------
// int64-vs-int32 detection + conversion of index arrays (clamped to [0,N)).
// ---------------------------------------------------------------------------
__global__ void init_kernel(int* deg, int* fill, int* flags) {
    int i = blockIdx.x * 256 + threadIdx.x;
    if (i < N_NODES) { deg[i] = 0; fill[i] = 0; }
    if (i < 2) flags[i] = 0;
}
__global__ void detect_kernel(const int* __restrict__ raw, int nhalf, int* __restrict__ flag) {
    int i = blockIdx.x * 256 + threadIdx.x;
    if (i < nhalf && raw[2 * i + 1] != 0) atomicOr(flag, 1);
}
__global__ void convert_idx_kernel(const void* __restrict__ raw, int n,
                                   const int* __restrict__ flag, int* __restrict__ out) {
    int i = blockIdx.x * 256 + threadIdx.x;
    if (i >= n) return;
    int v = (*flag) ? ((const int*)raw)[i] : (int)((const long long*)raw)[i];
    out[i] = v & NODE_MASK;
}

// ---------------------------------------------------------------------------
// f32 -> bf16 elementwise convert (vectorized)
// ---------------------------------------------------------------------------
__global__ void cvt_bf16_kernel(const float* __restrict__ in, ushort_t* __restrict__ out, int n4) {
    int i = blockIdx.x * 256 + threadIdx.x;
    if (i >= n4) return;
    f32x4 v = *(const f32x4*)(in + i * 4);
    ushort_t o0 = f2bf(v[0]), o1 = f2bf(v[1]), o2 = f2bf(v[2]), o3 = f2bf(v[3]);
    unsigned long long pk = (unsigned long long)o0 | ((unsigned long long)o1 << 16)
                          | ((unsigned long long)o2 << 32) | ((unsigned long long)o3 << 48);
    *(unsigned long long*)(out + i * 4) = pk;
}

// ---------------------------------------------------------------------------
// f32 -> bf16 transpose: out[c][r] = (bf16)in[r][c]; in is R x Ccols f32.
// ---------------------------------------------------------------------------
__global__ __launch_bounds__(256) void transpose_cvt_kernel(
    const float* __restrict__ in, ushort_t* __restrict__ out, int R, int Ccols)
{
    __shared__ ushort_t tile[32][33];
    int tx = threadIdx.x & 31, ty = threadIdx.x >> 5;
    int x  = blockIdx.x * 32 + tx;
    int y0 = blockIdx.y * 32;
#pragma unroll
    for (int i = 0; i < 4; ++i)
        tile[ty + i * 8][tx] = f2bf(in[(size_t)(y0 + ty + i * 8) * Ccols + x]);
    __syncthreads();
#pragma unroll
    for (int i = 0; i < 4; ++i)
        out[(size_t)(blockIdx.x * 32 + ty + i * 8) * R + y0 + tx] = tile[tx][ty + i * 8];
}

// ---------------------------------------------------------------------------
// bf16 MFMA GEMM:  C[M,N] = A[M,K]*Bt[N,K]^T.  128x128 tile, BK=64, 256 thr,
// global_load_lds w=16 staging, XOR swizzle on global source address.
// XCD-aware block remap (bijective): xcd = lin&7 owns a contiguous by-chunk.
// Split-K: z-slice covers [z*ksz, (z+1)*ksz); slice output goes to
//   bf16  C + z*M*N   (C branch)   or   f32  Cp + z*M*N  (Cp branch).
// Optional fused att-logit partials (GEMM1 only, deterministic, no atomics):
//   Ps/Pd[(head*12 + slot)*M + row], slot = (bx%bx_per_head)*2 + wn; every
//   slot is written exactly once by one wave -> full coverage, no init needed.
// ---------------------------------------------------------------------------
__global__ __launch_bounds__(256) void gemm_bt_kernel(
    const ushort_t* __restrict__ A, const ushort_t* __restrict__ Bt,
    ushort_t* __restrict__ C, const float* __restrict__ bias,
    float* __restrict__ Cp,
    const float* __restrict__ att_s, const float* __restrict__ att_d,
    float* __restrict__ Ps, float* __restrict__ Pd, int bx_per_head,
    int M, int N, int K, int ksz)
{
    __shared__ ushort_t lsA[128 * 64];
    __shared__ ushort_t lsB[128 * 64];

    const int tid  = threadIdx.x;
    const int lane = tid & 63;
    const int wave = tid >> 6;
    const int wm = wave >> 1, wn = wave & 1;

    // XCD-aware swizzle (dispatch linearizes x-fastest; XCD = lin%8)
    const int GX = gridDim.x, GY = gridDim.y;
    const int lin = blockIdx.y * GX + blockIdx.x;
    const int byg = (GY >= 8) ? (GY >> 3) : 1;
    const int xcd = lin & 7;
    const int jj  = lin >> 3;
    const int bx  = (GY >= 8) ? (jj / byg) : blockIdx.x;
    const int by  = (GY >= 8) ? (xcd * byg + (jj % byg)) : blockIdx.y;

    const f32x4 zero = {0.f, 0.f, 0.f, 0.f};
    f32x4 acc[4][4];
#pragma unroll
    for (int i = 0; i < 4; ++i)
#pragma unroll
        for (int j = 0; j < 4; ++j) acc[i][j] = zero;

    const int l8 = lane >> 3;   // row within 8-row group
    const int c8 = lane & 7;    // 16B chunk slot
    const int q  = lane >> 4;   // quad
    const int rl = lane & 15;

    const int kbeg = blockIdx.z * ksz;
    for (int kt = kbeg; kt < kbeg + ksz; kt += 64) {
        __syncthreads();   // previous tile fully consumed
#pragma unroll
        for (int i = 0; i < 4; ++i) {
            int rbase = wave * 32 + i * 8;      // wave-uniform
            int row   = rbase + l8;             // per-lane
            int gch   = c8 ^ (row & 7);         // swizzle on source
            const ushort_t* gA = A  + (size_t)(by * 128 + row) * K + kt + gch * 8;
            const ushort_t* gB = Bt + (size_t)(bx * 128 + row) * K + kt + gch * 8;
            __builtin_amdgcn_global_load_lds((gas_ptr)gA, (las_ptr)(lsA + rbase * 64), 16, 0, 0);
            __builtin_amdgcn_global_load_lds((gas_ptr)gB, (las_ptr)(lsB + rbase * 64), 16, 0, 0);
        }
        __syncthreads();   // vmcnt drained by barrier semantics
#pragma unroll
        for (int s = 0; s < 2; ++s) {
            bf16x8 af[4], bfv[4];
#pragma unroll
            for (int i = 0; i < 4; ++i) {
                int Ra = wm * 64 + i * 16 + rl;
                af[i]  = *(const bf16x8*)(lsA + Ra * 64 + (((s * 4 + q) ^ (Ra & 7)) * 8));
                int Rb = wn * 64 + i * 16 + rl;
                bfv[i] = *(const bf16x8*)(lsB + Rb * 64 + (((s * 4 + q) ^ (Rb & 7)) * 8));
            }
#pragma unroll
            for (int i = 0; i < 4; ++i)
#pragma unroll
                for (int j = 0; j < 4; ++j)
                    acc[i][j] = __builtin_amdgcn_mfma_f32_16x16x32_bf16(af[i], bfv[j], acc[i][j], 0, 0, 0);
        }
    }
    // epilogue: C/D layout col=lane&15, row=quad*4+reg (m89-verified)
    if (Cp) {
        float* Cpz = Cp + (size_t)blockIdx.z * M * N;
#pragma unroll
        for (int j = 0; j < 4; ++j) {
            int col = bx * 128 + wn * 64 + j * 16 + rl;
#pragma unroll
            for (int i = 0; i < 4; ++i)
#pragma unroll
                for (int t = 0; t < 4; ++t) {
                    int row = by * 128 + wm * 64 + i * 16 + q * 4 + t;
                    Cpz[(size_t)row * N + col] = acc[i][j][t];
                }
        }
    } else {
        ushort_t* Cz = C + (size_t)blockIdx.z * M * N;
#pragma unroll
        for (int j = 0; j < 4; ++j) {
            int col = bx * 128 + wn * 64 + j * 16 + rl;
            float bv = bias ? bias[col] : 0.0f;
#pragma unroll
            for (int i = 0; i < 4; ++i)
#pragma unroll
                for (int t = 0; t < 4; ++t) {
                    int row = by * 128 + wm * 64 + i * 16 + q * 4 + t;
                    Cz[(size_t)row * N + col] = f2bf(acc[i][j][t] + bv);
                }
        }
    }
    if (bx_per_head > 0) {
        const int head = bx / bx_per_head;
        const int slot = (bx % bx_per_head) * 2 + wn;   // 0..11, unique per wave
        const int colh = (bx % bx_per_head) * 128 + wn * 64 + rl;
        float as_[4], ad_[4];
#pragma unroll
        for (int j = 0; j < 4; ++j) {
            as_[j] = att_s[head * 768 + colh + j * 16];
            ad_[j] = att_d[head * 768 + colh + j * 16];
        }
        float* ps = Ps + (size_t)(head * 12 + slot) * M;
        float* pd = Pd + (size_t)(head * 12 + slot) * M;
#pragma unroll
        for (int i = 0; i < 4; ++i)
#pragma unroll
            for (int t = 0; t < 4; ++t) {
                float p1 = 0.f, p2 = 0.f;
#pragma unroll
                for (int j = 0; j < 4; ++j) {
                    p1 += acc[i][j][t] * as_[j];
                    p2 += acc[i][j][t] * ad_[j];
                }
#pragma unroll
                for (int o = 1; o < 16; o <<= 1) {
                    p1 += __shfl_xor(p1, o);
                    p2 += __shfl_xor(p2, o);
                }
                if (rl == 0) {
                    int row = by * 128 + wm * 64 + i * 16 + q * 4 + t;
                    ps[row] = p1;
                    pd[row] = p2;
                }
            }
    }
}

// ---------------------------------------------------------------------------
// Reduce att1 partials: a_s1[n*8+h] = sum over 12 slots of Ps[(h*12+s)*M + n].
// gid = h*8192 + n -> coalesced partial reads.
// ---------------------------------------------------------------------------
__global__ void att1red_kernel(const float* __restrict__ Ps, const float* __restrict__ Pd,
                               float* __restrict__ a_s, float* __restrict__ a_d)
{
    int gid = blockIdx.x * 256 + threadIdx.x;   // 0..65535
    int h = gid >> 13, n = gid & 8191;
    float s = 0.f, d = 0.f;
#pragma unroll
    for (int slot = 0; slot < 12; ++slot) {
        s += Ps[((size_t)(h * 12 + slot) << 13) + n];
        d += Pd[((size_t)(h * 12 + slot) << 13) + n];
    }
    a_s[n * 8 + h] = s;
    a_d[n * 8 + h] = d;
}

// ---------------------------------------------------------------------------
// CSR build by dst (count -> scan -> scatter). Indices pre-clamped to [0,N).
// ---------------------------------------------------------------------------
__global__ void indeg_kernel(const int* __restrict__ eic, int* __restrict__ deg) {
    int e = blockIdx.x * 256 + threadIdx.x;
    if (e >= E_TOT) return;
    int dst = (e < E_EDGES) ? eic[E_EDGES + e] : (e - E_EDGES);
    atomicAdd(&deg[dst], 1);
}
__global__ __launch_bounds__(256) void scan_kernel(const int* __restrict__ deg, int* __restrict__ rowptr) {
    __shared__ int part[256];
    int t = threadIdx.x;
    int local[32];
    int s = 0;
#pragma unroll
    for (int i = 0; i < 32; ++i) { local[i] = deg[t * 32 + i]; s += local[i]; }
    part[t] = s;
    __syncthreads();
    for (int off = 1; off < 256; off <<= 1) {
        int v = (t >= off) ? part[t - off] : 0;
        __syncthreads();
        part[t] += v;
        __syncthreads();
    }
    int run = (t == 0) ? 0 : part[t - 1];
#pragma unroll
    for (int i = 0; i < 32; ++i) { rowptr[t * 32 + i] = run; run += local[i]; }
    if (t == 255) rowptr[N_NODES] = run;
}
__global__ void scatter_kernel(const int* __restrict__ eic, const int* __restrict__ rowptr,
                               int* __restrict__ fill, int* __restrict__ csr_src) {
    int e = blockIdx.x * 256 + threadIdx.x;
    if (e >= E_TOT) return;
    int src, dst;
    if (e < E_EDGES) { src = eic[e]; dst = eic[E_EDGES + e]; }
    else             { src = e - E_EDGES; dst = src; }
    int pos = rowptr[dst] + atomicAdd(&fill[dst], 1);
    csr_src[pos] = src;
}

// ---------------------------------------------------------------------------
// Split-K consumer: h2 = bf16(sum of 4 bf16 Cb slices) + fused layer-2
// attention logits (1 head). Block per node, 256 threads.
// ---------------------------------------------------------------------------
__global__ __launch_bounds__(256) void cvtatt_kernel(
    const ushort_t* __restrict__ Cb, ushort_t* __restrict__ h2,
    const float* __restrict__ att_s, const float* __restrict__ att_d,
    float* __restrict__ a_s, float* __restrict__ a_d)
{
    __shared__ float ps[4], pd[4];
    const int n = blockIdx.x, t = threadIdx.x;
    const size_t SL = (size_t)N_NODES * 768;
    const ushort_t* row = Cb + (size_t)n * 768;
    float v0 = bf2f(row[t])       + bf2f(row[SL + t])       + bf2f(row[2 * SL + t])       + bf2f(row[3 * SL + t]);
    float v1 = bf2f(row[t + 256]) + bf2f(row[SL + t + 256]) + bf2f(row[2 * SL + t + 256]) + bf2f(row[3 * SL + t + 256]);
    float v2 = bf2f(row[t + 512]) + bf2f(row[SL + t + 512]) + bf2f(row[2 * SL + t + 512]) + bf2f(row[3 * SL + t + 512]);
    h2[(size_t)n * 768 + t]       = f2bf(v0);
    h2[(size_t)n * 768 + t + 256] = f2bf(v1);
    h2[(size_t)n * 768 + t + 512] = f2bf(v2);
    float s1 = v0 * att_s[t] + v1 * att_s[t + 256] + v2 * att_s[t + 512];
    float s2 = v0 * att_d[t] + v1 * att_d[t + 256] + v2 * att_d[t + 512];
#pragma unroll
    for (int o = 32; o > 0; o >>= 1) {
        s1 += __shfl_down(s1, o);
        s2 += __shfl_down(s2, o);
    }
    if ((t & 63) == 0) { ps[t >> 6] = s1; pd[t >> 6] = s2; }
    __syncthreads();
    if (t == 0) {
        a_s[n] = ps[0] + ps[1] + ps[2] + ps[3];
        a_d[n] = pd[0] + pd[1] + pd[2] + pd[3];
    }
}

// ---------------------------------------------------------------------------
// Aggregation layer 1 (8 heads, 6144 ch): grid (node, half). 192 thr x 16 ch;
// per-head softmax over incoming edges; edge loop unrolled x4; ELU -> bf16.
// ---------------------------------------------------------------------------
__global__ __launch_bounds__(192) void agg8_kernel(
    const ushort_t* __restrict__ h, const float* __restrict__ a_s, const float* __restrict__ a_d,
    const int* __restrict__ rowptr, const int* __restrict__ csr_src,
    const float* __restrict__ bias, ushort_t* __restrict__ out)
{
    const int n = blockIdx.x;
    const int half = blockIdx.y;
    const int tid = threadIdx.x;
    const int base = rowptr[n];
    const int deg  = rowptr[n + 1] - base;

    __shared__ float s_m[8], s_rd[8], s_adst[8];
    __shared__ int   s_src[64];
    __shared__ float s_w[64][8];

    if (tid < 8) {
        float adst = a_d[n * 8 + tid];
        float m = -1e30f;
        for (int e = 0; e < deg; ++e) {
            float scv = a_s[csr_src[base + e] * 8 + tid] + adst;
            scv = scv > 0.f ? scv : 0.2f * scv;
            m = fmaxf(m, scv);
        }
        float den = 0.f;
        for (int e = 0; e < deg; ++e) {
            float scv = a_s[csr_src[base + e] * 8 + tid] + adst;
            scv = scv > 0.f ? scv : 0.2f * scv;
            den += __expf(scv - m);
        }
        s_m[tid] = m; s_rd[tid] = 1.0f / (den + 1e-16f); s_adst[tid] = adst;
    }
    __syncthreads();

    float acc[16];
#pragma unroll
    for (int i = 0; i < 16; ++i) acc[i] = 0.f;
    const int c0   = half * 3072 + tid * 16;
    const int myhd = (half << 2) + tid / 48;

    for (int cs = 0; cs < deg; cs += 64) {
        int cnt = min(64, deg - cs);
        __syncthreads();
        for (int idx = tid; idx < cnt; idx += 192) s_src[idx] = csr_src[base + cs + idx];
        __syncthreads();
        for (int idx = tid; idx < cnt * 8; idx += 192) {
            int e = idx >> 3, hd = idx & 7;
            float scv = a_s[s_src[e] * 8 + hd] + s_adst[hd];
            scv = scv > 0.f ? scv : 0.2f * scv;
            s_w[e][hd] = __expf(scv - s_m[hd]) * s_rd[hd];
        }
        __syncthreads();
        int e = 0;
        for (; e + 3 < cnt; e += 4) {
            const ushort_t* p0 = h + (size_t)s_src[e]     * F1 + c0;
            const ushort_t* p1 = h + (size_t)s_src[e + 1] * F1 + c0;
            const ushort_t* p2 = h + (size_t)s_src[e + 2] * F1 + c0;
            const ushort_t* p3 = h + (size_t)s_src[e + 3] * F1 + c0;
            ushort8 a0 = *(const ushort8*)(p0), a1 = *(const ushort8*)(p0 + 8);
            ushort8 b0 = *(const ushort8*)(p1), b1 = *(const ushort8*)(p1 + 8);
            ushort8 c0v = *(const ushort8*)(p2), c1v = *(const ushort8*)(p2 + 8);
            ushort8 d0 = *(const ushort8*)(p3), d1 = *(const ushort8*)(p3 + 8);
            float w0 = s_w[e][myhd], w1 = s_w[e + 1][myhd];
            float w2 = s_w[e + 2][myhd], w3 = s_w[e + 3][myhd];
#pragma unroll
            for (int i = 0; i < 8; ++i) {
                acc[i]     += w0 * bf2f(a0[i]) + w1 * bf2f(b0[i]) + w2 * bf2f(c0v[i]) + w3 * bf2f(d0[i]);
                acc[8 + i] += w0 * bf2f(a1[i]) + w1 * bf2f(b1[i]) + w2 * bf2f(c1v[i]) + w3 * bf2f(d1[i]);
            }
        }
        for (; e < cnt; ++e) {
            const ushort_t* p0 = h + (size_t)s_src[e] * F1 + c0;
            ushort8 a0 = *(const ushort8*)(p0), a1 = *(const ushort8*)(p0 + 8);
            float w0 = s_w[e][myhd];
#pragma unroll
            for (int i = 0; i < 8; ++i) {
                acc[i]     += w0 * bf2f(a0[i]);
                acc[8 + i] += w0 * bf2f(a1[i]);
            }
        }
    }
#pragma unroll
    for (int i = 0; i < 16; ++i) {
        float v = acc[i] + bias[c0 + i];
        v = v > 0.f ? v : (__expf(v) - 1.0f);   // ELU
        out[(size_t)n * F1 + c0 + i] = f2bf(v);
    }
}

// ---------------------------------------------------------------------------
// Aggregation layer 2 (1 head, 768 ch): block per node, + b2, no activation.
// ---------------------------------------------------------------------------
__global__ __launch_bounds__(256) void agg1_kernel(
    const ushort_t* __restrict__ h, const float* __restrict__ a_s, const float* __restrict__ a_d,
    const int* __restrict__ rowptr, const int* __restrict__ csr_src,
    const float* __restrict__ bias, ushort_t* __restrict__ out)
{
    const int n = blockIdx.x;
    const int tid = threadIdx.x;
    const int base = rowptr[n];
    const int deg  = rowptr[n + 1] - base;
    __shared__ float s_m, s_rd, s_adst;
    __shared__ int   s_src[64];
    __shared__ float s_w[64];
    if (tid == 0) {
        float adst = a_d[n];
        float m = -1e30f;
        for (int e = 0; e < deg; ++e) {
            float scv = a_s[csr_src[base + e]] + adst;
            scv = scv > 0.f ? scv : 0.2f * scv;
            m = fmaxf(m, scv);
        }
        float den = 0.f;
        for (int e = 0; e < deg; ++e) {
            float scv = a_s[csr_src[base + e]] + adst;
            scv = scv > 0.f ? scv : 0.2f * scv;
            den += __expf(scv - m);
        }
        s_m = m; s_rd = 1.0f / (den + 1e-16f); s_adst = adst;
    }
    __syncthreads();
    float acc0 = 0.f, acc1 = 0.f, acc2 = 0.f;
    const int c0 = tid * 3;
    for (int cs = 0; cs < deg; cs += 64) {
        int cnt = min(64, deg - cs);
        __syncthreads();
        for (int idx = tid; idx < cnt; idx += 256) s_src[idx] = csr_src[base + cs + idx];
        __syncthreads();
        for (int idx = tid; idx < cnt; idx += 256) {
            float scv = a_s[s_src[idx]] + s_adst;
            scv = scv > 0.f ? scv : 0.2f * scv;
            s_w[idx] = __expf(scv - s_m) * s_rd;
        }
        __syncthreads();
        for (int e = 0; e < cnt; ++e) {
            const ushort_t* hp = h + (size_t)s_src[e] * C_CH + c0;
            float w = s_w[e];
            acc0 += w * bf2f(hp[0]);
            acc1 += w * bf2f(hp[1]);
            acc2 += w * bf2f(hp[2]);
        }
    }
    out[(size_t)n * C_CH + c0 + 0] = f2bf(acc0 + bias[c0 + 0]);
    out[(size_t)n * C_CH + c0 + 1] = f2bf(acc1 + bias[c0 + 1]);
    out[(size_t)n * C_CH + c0 + 2] = f2bf(acc2 + bias[c0 + 2]);
}

// ---------------------------------------------------------------------------
// Build fc input rows: Afc[m] = concat(out2[mask[m]], xb[mask[m]])  (bf16)
// ---------------------------------------------------------------------------
__global__ void gatherfc_kernel(const ushort_t* __restrict__ out2, const ushort_t* __restrict__ xb,
                                const int* __restrict__ maskc, ushort_t* __restrict__ Afc)
{
    int m = blockIdx.x, t = threadIdx.x;
    int mi = maskc[m];
    const ushort4v* p1 = (const ushort4v*)(out2 + (size_t)mi * 768);
    const ushort4v* p2 = (const ushort4v*)(xb   + (size_t)mi * 768);
    ushort4v* q1 = (ushort4v*)(Afc + (size_t)m * 1536);
    ushort4v* q2 = (ushort4v*)(Afc + (size_t)m * 1536 + 768);
    if (t < 192) { q1[t] = p1[t]; q2[t] = p2[t]; }
}

// ---------------------------------------------------------------------------
// Classifier over fc split-K slices: fcrow[c] = sum_z fcp[z][m*768+c] + fc_b[c];
// out[m,k] = <fcrow, cls_w[:,k]> + cls_b[k]. One wave per row.
// ---------------------------------------------------------------------------
__global__ __launch_bounds__(256) void cls_kernel(
    const float* __restrict__ fcp, const float* __restrict__ fc_b,
    const float* __restrict__ cls_w, const float* __restrict__ cls_b,
    float* __restrict__ out)
{
    int m = blockIdx.x * 4 + (threadIdx.x >> 6);
    int lane = threadIdx.x & 63;
    const size_t SL = (size_t)M_MASK * 768;
    float a0 = 0.f, a1 = 0.f;
    const float* row = fcp + (size_t)m * 768;
    for (int i = lane; i < 768; i += 64) {
        float v = row[i] + row[SL + i] + row[2 * SL + i] + row[3 * SL + i] + fc_b[i];
        a0 += v * cls_w[i * 2 + 0];
        a1 += v * cls_w[i * 2 + 1];
    }
#pragma unroll
    for (int off = 32; off > 0; off >>= 1) {
        a0 += __shfl_down(a0, off);
        a1 += __shfl_down(a1, off);
    }
    if (lane == 0) {
        out[m * 2 + 0] = a0 + cls_b[0];
        out[m * 2 + 1] = a1 + cls_b[1];
    }
}

extern "C" void kernel_launch(void* const* d_in, const int* in_sizes, int n_in,
                              void* d_out, int out_size, void* d_ws, size_t ws_size,
                              hipStream_t stream)
{
    const float* x        = (const float*)d_in[0];
    const void*  ei_raw   = d_in[1];
    const void*  mask_raw = d_in[2];
    const float* W1       = (const float*)d_in[3];
    const float* att_src1 = (const float*)d_in[4];
    const float* att_dst1 = (const float*)d_in[5];
    const float* b1       = (const float*)d_in[6];
    const float* W2       = (const float*)d_in[7];
    const float* att_src2 = (const float*)d_in[8];
    const float* att_dst2 = (const float*)d_in[9];
    const float* b2       = (const float*)d_in[10];
    const float* fc_w     = (const float*)d_in[11];
    const float* fc_b     = (const float*)d_in[12];
    const float* cls_w    = (const float*)d_in[13];
    const float* cls_b    = (const float*)d_in[14];
    float* out = (float*)d_out;

    // ---- workspace layout ----
    char* ws = (char*)d_ws;
    size_t off = 0;
    auto alloc = [&](size_t bytes) { char* p = ws + off; off = (off + bytes + 255) & ~(size_t)255; return p; };
    int*   flags  = (int*)alloc(2 * 4);
    int*   eic    = (int*)alloc((size_t)2 * E_EDGES * 4);
    int*   maskc  = (int*)alloc((size_t)M_MASK * 4);
    int*   deg    = (int*)alloc(N_NODES * 4);
    int*   fill   = (int*)alloc(N_NODES * 4);
    int*   rowptr = (int*)alloc((N_NODES + 1) * 4);
    int*   csr    = (int*)alloc(E_TOT * 4);
    float* a_s1   = (float*)alloc((size_t)N_NODES * 8 * 4);
    float* a_d1   = (float*)alloc((size_t)N_NODES * 8 * 4);
    float* a_s2   = (float*)alloc((size_t)N_NODES * 4);
    float* a_d2   = (float*)alloc((size_t)N_NODES * 4);
    float* Ps     = (float*)alloc((size_t)8 * 12 * N_NODES * 4);   // 3.1 MB
    float* Pd     = (float*)alloc((size_t)8 * 12 * N_NODES * 4);   // 3.1 MB
    ushort_t* W1t  = (ushort_t*)alloc((size_t)D_IN * F1 * 2);
    ushort_t* W2t  = (ushort_t*)alloc((size_t)F1 * C_CH * 2);
    ushort_t* fcwt = (ushort_t*)alloc((size_t)1536 * 768 * 2);
    ushort_t* xb   = (ushort_t*)alloc((size_t)N_NODES * D_IN * 2);
    char* region1 = alloc((size_t)N_NODES * F1 * 2);   // h1 -> Cb(4 bf16 slices) -> fcp
    char* region2 = alloc((size_t)N_NODES * F1 * 2);   // out1 -> {out2, h2, Afc}
    // region1 phases:
    ushort_t* h1  = (ushort_t*)region1;                 // layer-1 GEMM out (100.7MB)
    ushort_t* Cb  = (ushort_t*)region1;                 // 4 x 12.6MB bf16 split-K slices
    float*    fcp = (float*)region1;                    // 4 x 6.3MB fc split-K slices
    // region2 phases:
    ushort_t* out1 = (ushort_t*)region2;                // agg8 out (100.7MB), GEMM2 A
    ushort_t* out2 = (ushort_t*)region2;                // agg1 out (12.6MB), after out1 dead
    ushort_t* h2   = (ushort_t*)(region2 + (16u << 20)); // 12.6MB @ 16MiB
    ushort_t* Afc  = (ushort_t*)(region2 + (32u << 20)); // 6.3MB  @ 32MiB

    // ---- index conversion + CSR build ----
    init_kernel<<<N_NODES / 256, 256, 0, stream>>>(deg, fill, flags);
    detect_kernel<<<(E_EDGES + 255) / 256, 256, 0, stream>>>((const int*)ei_raw, E_EDGES, &flags[0]);
    detect_kernel<<<(M_MASK / 2 + 255) / 256, 256, 0, stream>>>((const int*)mask_raw, M_MASK / 2, &flags[1]);
    convert_idx_kernel<<<(2 * E_EDGES + 255) / 256, 256, 0, stream>>>(ei_raw, 2 * E_EDGES, &flags[0], eic);
    convert_idx_kernel<<<(M_MASK + 255) / 256, 256, 0, stream>>>(mask_raw, M_MASK, &flags[1], maskc);
    indeg_kernel<<<E_TOT / 256, 256, 0, stream>>>(eic, deg);
    scan_kernel<<<1, 256, 0, stream>>>(deg, rowptr);
    scatter_kernel<<<E_TOT / 256, 256, 0, stream>>>(eic, rowptr, fill, csr);

    // ---- f32 -> bf16 converts: x, and weight transposes to [N,K] ----
    cvt_bf16_kernel<<<(N_NODES * D_IN / 4 + 255) / 256, 256, 0, stream>>>(x, xb, N_NODES * D_IN / 4);
    transpose_cvt_kernel<<<dim3(F1 / 32, D_IN / 32), 256, 0, stream>>>(W1, W1t, D_IN, F1);
    transpose_cvt_kernel<<<dim3(C_CH / 32, F1 / 32), 256, 0, stream>>>(W2, W2t, F1, C_CH);
    transpose_cvt_kernel<<<dim3(768 / 32, 1536 / 32), 256, 0, stream>>>(fc_w, fcwt, 1536, 768);

    // ---- layer 1: GEMM + fused att1 partials (plain stores), reduce, agg ----
    gemm_bt_kernel<<<dim3(F1 / 128, N_NODES / 128), 256, 0, stream>>>(
        xb, W1t, h1, nullptr, nullptr, att_src1, att_dst1, Ps, Pd, 6,
        N_NODES, F1, D_IN, D_IN);
    att1red_kernel<<<(N_NODES * 8) / 256, 256, 0, stream>>>(Ps, Pd, a_s1, a_d1);
    agg8_kernel<<<dim3(N_NODES, 2), 192, 0, stream>>>(h1, a_s1, a_d1, rowptr, csr, b1, out1);

    // ---- layer 2: split-K=4 into bf16 slices (h1 dead), cvt+att2, agg ----
    gemm_bt_kernel<<<dim3(C_CH / 128, N_NODES / 128, 4), 256, 0, stream>>>(
        out1, W2t, Cb, nullptr, nullptr, nullptr, nullptr, nullptr, nullptr, 0,
        N_NODES, C_CH, F1, F1 / 4);
    cvtatt_kernel<<<N_NODES, 256, 0, stream>>>(Cb, h2, att_src2, att_dst2, a_s2, a_d2);
    agg1_kernel<<<N_NODES, 256, 0, stream>>>(h2, a_s2, a_d2, rowptr, csr, b2, out2);  // out1 dead

    // ---- head: gather, fc split-K=4 f32 (Cb dead -> fcp), fused classifier ----
    gatherfc_kernel<<<M_MASK, 256, 0, stream>>>(out2, xb, maskc, Afc);
    gemm_bt_kernel<<<dim3(768 / 128, M_MASK / 128, 4), 256, 0, stream>>>(
        Afc, fcwt, nullptr, nullptr, fcp, nullptr, nullptr, nullptr, nullptr, 0,
        M_MASK, 768, 1536, 1536 / 4);
    cls_kernel<<<M_MASK / 4, 256, 0, stream>>>(fcp, fc_b, cls_w, cls_b, out);
}